// Round 4
// baseline (221.924 us; speedup 1.0000x reference)
//
#include <hip/hip_runtime.h>
#include <math.h>

// EqualtimeLayer: per (b,post): sort 1024 events by t = spike[b][pre]+delay[pre][post],
// prefix-sum (w, w*t) in sorted order, candidate tmp_k=(theta+cumwt)/cumw valid iff
// cumw>0 && tmp>=t_k && (k==last || tmp<=t_{k+1}); output = min valid tmp.
//
// R4: wave-per-task (64-thr blocks, ZERO barriers — LDS is wave-pipe-ordered),
// 1024 value-buckets over [0,1) + ballot-ranked overflow tail for t>=1,
// chunked (256) fixup+scan+candidates with exact early exit (crossing ~pos 120-250),
// rare exact fallback epoch re-sorts the overflow region if no crossing < 1.

#define B_TOT 32
#define PRE 1024
#define POST 1024
#define NBUCK 1024
#define BPW 8          // batches per wave

// ---- DPP helpers (gfx9 encodings) ----
template<int CTRL, int MASK>
__device__ __forceinline__ int dpp_add_i32(int v) {
    return v + __builtin_amdgcn_update_dpp(0, v, CTRL, MASK, 0xf, true);
}
template<int CTRL, int MASK>
__device__ __forceinline__ float dpp_add_f32(float v) {
    int t = __builtin_amdgcn_update_dpp(0, __float_as_int(v), CTRL, MASK, 0xf, true);
    return v + __int_as_float(t);
}
template<int CTRL>
__device__ __forceinline__ float dpp_min_f32(float v) {
    int t = __builtin_amdgcn_update_dpp(__float_as_int(v), __float_as_int(v), CTRL, 0xf, 0xf, false);
    return fminf(v, __int_as_float(t));
}
__device__ __forceinline__ int wave_iscan_i32(int v) {
    v = dpp_add_i32<0x111, 0xf>(v);
    v = dpp_add_i32<0x112, 0xf>(v);
    v = dpp_add_i32<0x114, 0xf>(v);
    v = dpp_add_i32<0x118, 0xf>(v);
    v = dpp_add_i32<0x142, 0xa>(v);
    v = dpp_add_i32<0x143, 0xc>(v);
    return v;
}
__device__ __forceinline__ float wave_iscan_f32(float v) {
    v = dpp_add_f32<0x111, 0xf>(v);
    v = dpp_add_f32<0x112, 0xf>(v);
    v = dpp_add_f32<0x114, 0xf>(v);
    v = dpp_add_f32<0x118, 0xf>(v);
    v = dpp_add_f32<0x142, 0xa>(v);
    v = dpp_add_f32<0x143, 0xc>(v);
    return v;
}
// full-wave min, result broadcast (uniform) to all lanes
__device__ __forceinline__ float wave_min_all(float v) {
    v = fminf(v, __shfl_down(v, 32));
    v = fminf(v, __shfl_down(v, 16));
    v = dpp_min_f32<0x140>(v);   // row_mirror
    v = dpp_min_f32<0x141>(v);   // half_mirror
    v = dpp_min_f32<0x4E>(v);    // quad_perm [2,3,0,1]
    v = dpp_min_f32<0xB1>(v);    // quad_perm [1,0,3,2]
    return __int_as_float(__builtin_amdgcn_readlane(__float_as_int(v), 0));
}

__device__ __forceinline__ int clamp_bucket(int k) {
    return k < 0 ? 0 : (k > NBUCK - 1 ? NBUCK - 1 : k);
}

// exclusive-scan NBUCK counts in s_cnt, repack as (off<<12)|cnt; return total.
__device__ __forceinline__ int scan_counts(int* s_cnt, int lane) {
    int4 v[4];
#pragma unroll
    for (int q = 0; q < 4; ++q) v[q] = reinterpret_cast<int4*>(s_cnt)[4 * lane + q];
    int c[16] = {v[0].x, v[0].y, v[0].z, v[0].w, v[1].x, v[1].y, v[1].z, v[1].w,
                 v[2].x, v[2].y, v[2].z, v[2].w, v[3].x, v[3].y, v[3].z, v[3].w};
    int ls[16]; int run = 0;
#pragma unroll
    for (int k = 0; k < 16; ++k) { run += c[k]; ls[k] = run; }
    int x = wave_iscan_i32(run);
    int excl = x - run;
    int o[16];
#pragma unroll
    for (int k = 0; k < 16; ++k) o[k] = ((excl + ls[k] - c[k]) << 12) | c[k];
#pragma unroll
    for (int q = 0; q < 4; ++q)
        reinterpret_cast<int4*>(s_cnt)[4 * lane + q] =
            make_int4(o[4 * q], o[4 * q + 1], o[4 * q + 2], o[4 * q + 3]);
    return __builtin_amdgcn_readlane(x, 63);
}

// Process sorted positions [lo,hi) in 256-chunks: fixup buckets based in chunk,
// scan (w, w*t), emit candidates, early-exit when mc <= chunk boundary time.
// Buckets for this range: index (t - t0f)*NBUCK, base = lo + (packed>>12).
__device__ __forceinline__ bool process_range(
    float2* s_tw, int* s_cnt, int lo, int hi, float t0f, float tEnd,
    float theta, int lane, float& cumW, float& cumWT, float& mOut, float& mLane)
{
    for (int pos0 = lo; pos0 < hi; pos0 += 256) {
        const int next = pos0 + 256;
        // ---- boundary time: min of the bucket holding position `next` (permutation-
        //      invariant, so safe pre-fixup); else epoch end time ----
        float t_bnd;
        if (next < hi) {
            float tx = s_tw[next].x;                      // uniform broadcast read
            int ki = clamp_bucket((int)((tx - t0f) * (float)NBUCK));
            int pk = s_cnt[ki];
            int bas = lo + (pk >> 12), cnt = pk & 0xfff;
            t_bnd = INFINITY;
            for (int q = 0; q < cnt; ++q) t_bnd = fminf(t_bnd, s_tw[bas + q].x);
        } else {
            t_bnd = tEnd;
        }
        // ---- fixup: exact in-bucket rank for buckets BASED in [pos0,next),
        //      including straddle tail beyond `next` (ownership = chunk of base).
        //      All rank-gathers complete before any rewrite (deferred). ----
        float ft[6], fw[6]; int fnp[6];
        bool more = true;
        int lastp = pos0 + lane;
#pragma unroll
        for (int s = 0; s < 6; ++s) {
            fnp[s] = -1;
            if (more) {
                int p = pos0 + 64 * s + lane;
                lastp = p;
                bool inr = false;
                if (p < hi) {
                    float2 e = s_tw[p];
                    int ki = clamp_bucket((int)((e.x - t0f) * (float)NBUCK));
                    int pk = s_cnt[ki];
                    int bas = lo + (pk >> 12), cnt = pk & 0xfff;
                    inr = (bas < next);
                    if (inr && bas >= pos0 && cnt > 1) {
                        int r = 0;
                        for (int q = bas; q < bas + cnt; ++q) {
                            float tq = s_tw[q].x;
                            r += ((tq < e.x) || (tq == e.x && q < p)) ? 1 : 0;
                        }
                        int np = bas + r;
                        if (np != p) { fnp[s] = np; ft[s] = e.x; fw[s] = e.y; }
                    }
                }
                more = __any(inr);
            }
        }
#pragma unroll
        for (int s = 0; s < 6; ++s)
            if (fnp[s] >= 0) s_tw[fnp[s]] = make_float2(ft[s], fw[s]);
        // pathological straddle (>384 positions in one bucket; unreachable for bench
        // data — immediate rewrite, tie-order within exactly-equal t may degrade):
        while (more) {
            int p = lastp + 64; lastp = p;
            bool inr = false;
            if (p < hi) {
                float2 e = s_tw[p];
                int ki = clamp_bucket((int)((e.x - t0f) * (float)NBUCK));
                int pk = s_cnt[ki];
                int bas = lo + (pk >> 12), cnt = pk & 0xfff;
                inr = (bas < next);
                if (inr && bas >= pos0 && cnt > 1) {
                    int r = 0;
                    for (int q = bas; q < bas + cnt; ++q) {
                        float tq = s_tw[q].x;
                        r += ((tq < e.x) || (tq == e.x && q < p)) ? 1 : 0;
                    }
                    int np = bas + r;
                    if (np != p) s_tw[np] = e;
                }
            }
            more = __any(inr);
        }
        // ---- scan (w, w*t) over chunk (blocked EPT=4) + candidates ----
        int p0 = pos0 + 4 * lane;
        float4 q0 = *reinterpret_cast<float4*>(&s_tw[p0]);
        float4 q1 = *reinterpret_cast<float4*>(&s_tw[p0 + 2]);
        float st[4] = {q0.x, q0.z, q1.x, q1.z};
        float sw[4] = {q0.y, q0.w, q1.y, q1.w};
#pragma unroll
        for (int jj = 0; jj < 4; ++jj)
            if (p0 + jj >= hi) { st[jj] = t_bnd; sw[jj] = 0.f; }  // hole trick: exact
        float cw[4], cwt[4];
        float aw = 0.f, awt = 0.f;
#pragma unroll
        for (int jj = 0; jj < 4; ++jj) {
            aw += sw[jj]; awt += sw[jj] * st[jj]; cw[jj] = aw; cwt[jj] = awt;
        }
        float xw  = wave_iscan_f32(aw);
        float xwt = wave_iscan_f32(awt);
        float baseW  = cumW  + xw  - aw;
        float baseWT = cumWT + xwt - awt;
        cumW  += __int_as_float(__builtin_amdgcn_readlane(__float_as_int(xw), 63));
        cumWT += __int_as_float(__builtin_amdgcn_readlane(__float_as_int(xwt), 63));
        float tn3 = __shfl_down(st[0], 1);
        if (lane == 63) tn3 = t_bnd;
#pragma unroll
        for (int jj = 0; jj < 4; ++jj) {
            float W  = baseW  + cw[jj];
            float WT = baseWT + cwt[jj];
            float tn = (jj < 3) ? st[jj + 1] : tn3;
            if (W > 0.f) {
                float tmp = (theta + WT) * __builtin_amdgcn_rcpf(W);
                if (tmp >= st[jj] && tmp <= tn) mLane = fminf(mLane, tmp);
            }
        }
        float mc = wave_min_all(mLane);
        mOut = mc;
        if (mc <= t_bnd) return true;  // later candidates >= their t_k >= t_bnd
    }
    return false;
}

__global__ __launch_bounds__(64, 4) void equaltime_kernel(
    const float* __restrict__ spikes,     // [B][PRE]
    const float* __restrict__ weights,    // [PRE][POST]
    const float* __restrict__ delays,     // [PRE][POST]
    const float* __restrict__ thresholds, // [POST]
    float* __restrict__ out)              // [B][POST]
{
    __shared__ __align__(16) float2 s_tw[PRE];    // 8 KB: sorted (t,w)
    __shared__ __align__(16) int    s_cnt[NBUCK]; // 4 KB: counts -> (off<<12|cnt)

    const int lane = threadIdx.x;
    // XCD-contiguous swizzle (L2 locality for the 16 posts sharing a 64B line)
    const int bx   = blockIdx.x;
    const int sbx  = (bx & 7) * 512 + (bx >> 3);
    const int post = sbx >> 2;            // 4 waves per post
    const int b0   = (sbx & 3) * BPW;
    const float theta = thresholds[post];

    // cache this post's delay/weight column in registers (amortized over BPW batches)
    float dly[16], wgt[16];
#pragma unroll
    for (int j = 0; j < 16; ++j) {
        int pre = lane * 16 + j;
        dly[j] = delays[pre * POST + post];
        wgt[j] = weights[pre * POST + post];
    }

    const unsigned long long below = (1ull << lane) - 1ull;

    for (int bi = 0; bi < BPW; ++bi) {
        const int b = b0 + bi;
        // zero counts: 8 conflict-free b64 writes
#pragma unroll
        for (int i = 0; i < 8; ++i)
            reinterpret_cast<int2*>(s_cnt)[lane + 64 * i] = make_int2(0, 0);

        // event times
        float tv[16];
        const float4* sp4 = reinterpret_cast<const float4*>(spikes + b * PRE + lane * 16);
#pragma unroll
        for (int q = 0; q < 4; ++q) {
            float4 s4 = sp4[q];
            tv[4 * q + 0] = s4.x + dly[4 * q + 0];
            tv[4 * q + 1] = s4.y + dly[4 * q + 1];
            tv[4 * q + 2] = s4.z + dly[4 * q + 2];
            tv[4 * q + 3] = s4.w + dly[4 * q + 3];
        }

        // histogram epoch 0: buckets [0,1); t>=1 -> ballot-ranked overflow tail
        int rnk[16];
        int ovrun = 0;
        float minov = INFINITY;
#pragma unroll
        for (int j = 0; j < 16; ++j) {
            int ki = (int)(tv[j] * (float)NBUCK);
            bool ov = (ki >= NBUCK);
            unsigned long long mk = __ballot(ov);
            if (ov) {
                rnk[j] = ovrun + (int)__popcll(mk & below);
                minov = fminf(minov, tv[j]);
            } else {
                rnk[j] = atomicAdd(&s_cnt[ki], 1);
            }
            ovrun += (int)__popcll(mk);
        }
        minov = wave_min_all(minov);   // INF if no overflow

        const int N_low = scan_counts(s_cnt, lane);

        // scatter (overflow tail unsorted at [N_low,1024))
#pragma unroll
        for (int j = 0; j < 16; ++j) {
            int ki = (int)(tv[j] * (float)NBUCK);
            int pos = (ki >= NBUCK) ? (N_low + rnk[j])
                                    : ((s_cnt[ki] >> 12) + rnk[j]);
            s_tw[pos] = make_float2(tv[j], wgt[j]);
        }

        // chunked solve with early exit
        float cumW = 0.f, cumWT = 0.f, mOut = INFINITY, mLane = INFINITY;
        bool done = process_range(s_tw, s_cnt, 0, N_low, 0.f, minov, theta, lane,
                                  cumW, cumWT, mOut, mLane);

        if (!done && N_low < PRE) {
            // ---- rare exact fallback: sort & process the [1,2) tail ----
#pragma unroll
            for (int i = 0; i < 8; ++i)
                reinterpret_cast<int2*>(s_cnt)[lane + 64 * i] = make_int2(0, 0);
#pragma unroll
            for (int j = 0; j < 16; ++j) {
                if ((int)(tv[j] * (float)NBUCK) >= NBUCK) {
                    int ki = clamp_bucket((int)((tv[j] - 1.0f) * (float)NBUCK));
                    rnk[j] = atomicAdd(&s_cnt[ki], 1);
                }
            }
            (void)scan_counts(s_cnt, lane);
#pragma unroll
            for (int j = 0; j < 16; ++j) {
                if ((int)(tv[j] * (float)NBUCK) >= NBUCK) {
                    int ki = clamp_bucket((int)((tv[j] - 1.0f) * (float)NBUCK));
                    int pos = N_low + (s_cnt[ki] >> 12) + rnk[j];
                    s_tw[pos] = make_float2(tv[j], wgt[j]);
                }
            }
            done = process_range(s_tw, s_cnt, N_low, PRE, 1.0f, INFINITY, theta, lane,
                                 cumW, cumWT, mOut, mLane);
        }

        if (lane == 0) out[b * POST + post] = mOut;
    }
}

extern "C" void kernel_launch(void* const* d_in, const int* in_sizes, int n_in,
                              void* d_out, int out_size, void* d_ws, size_t ws_size,
                              hipStream_t stream) {
    const float* spikes     = (const float*)d_in[0]; // [32,1024]
    const float* weights    = (const float*)d_in[1]; // [1024,1024]
    const float* delays     = (const float*)d_in[2]; // [1024,1024]
    const float* thresholds = (const float*)d_in[3]; // [1024]
    float* outp = (float*)d_out;                     // [32,1024]

    dim3 grid(POST * (B_TOT / BPW)); // 4096 single-wave workgroups
    dim3 block(64);
    equaltime_kernel<<<grid, block, 0, stream>>>(spikes, weights, delays, thresholds, outp);
}

// Round 5
// 148.757 us; speedup vs baseline: 1.4919x; 1.4919x over previous
//
#include <hip/hip_runtime.h>
#include <math.h>

// EqualtimeLayer: per (b,post): sort 1024 events by t = spike[b][pre]+delay[pre][post],
// prefix-sum (w, w*t) in sorted order, candidate tmp_k=(theta+cumwt)/cumw valid iff
// cumw>0 && tmp>=t_k && (k==last || tmp<=t_{k+1}); output = min valid tmp.
//
// R5 = R3 shell (256 thr, 4 waves, EPT=4, counting sort 1024 buckets over [0,2))
// + chunked (256-pos) fixup/scan/candidates with EXACT early exit: crossing lands
// at sorted pos ~123 (E[V(t)]=8.53t^3 => t*~0.49), so ~1.2 of 4 chunks run.
// Split s_t/s_w arrays (4B: random scatter/gather 2-way-aliased = free, m136).

#define B_TOT 32
#define PRE 1024
#define POST 1024
#define NBUCK 1024
#define TPB 256
#define EPT 4
#define B_PER_WG 16
#define CHUNK 256

// ---- DPP helpers (gfx9 encodings) ----
template<int CTRL, int MASK>
__device__ __forceinline__ int dpp_add_i32(int v) {
    return v + __builtin_amdgcn_update_dpp(0, v, CTRL, MASK, 0xf, true);
}
template<int CTRL, int MASK>
__device__ __forceinline__ float dpp_add_f32(float v) {
    int t = __builtin_amdgcn_update_dpp(0, __float_as_int(v), CTRL, MASK, 0xf, true);
    return v + __int_as_float(t);
}
template<int CTRL>
__device__ __forceinline__ float dpp_min_f32(float v) {
    int t = __builtin_amdgcn_update_dpp(__float_as_int(v), __float_as_int(v), CTRL, 0xf, 0xf, false);
    return fminf(v, __int_as_float(t));
}
__device__ __forceinline__ int wave_iscan_i32(int v) {
    v = dpp_add_i32<0x111, 0xf>(v);
    v = dpp_add_i32<0x112, 0xf>(v);
    v = dpp_add_i32<0x114, 0xf>(v);
    v = dpp_add_i32<0x118, 0xf>(v);
    v = dpp_add_i32<0x142, 0xa>(v);
    v = dpp_add_i32<0x143, 0xc>(v);
    return v;
}
__device__ __forceinline__ float wave_iscan_f32(float v) {
    v = dpp_add_f32<0x111, 0xf>(v);
    v = dpp_add_f32<0x112, 0xf>(v);
    v = dpp_add_f32<0x114, 0xf>(v);
    v = dpp_add_f32<0x118, 0xf>(v);
    v = dpp_add_f32<0x142, 0xa>(v);
    v = dpp_add_f32<0x143, 0xc>(v);
    return v;
}
__device__ __forceinline__ float wave_min_f32(float v) {
    v = fminf(v, __shfl_down(v, 32));
    v = fminf(v, __shfl_down(v, 16));
    v = dpp_min_f32<0x140>(v);   // row_mirror
    v = dpp_min_f32<0x141>(v);   // half_mirror
    v = dpp_min_f32<0x4E>(v);    // quad_perm [2,3,0,1]
    v = dpp_min_f32<0xB1>(v);    // quad_perm [1,0,3,2]
    return v;
}

__global__ __launch_bounds__(TPB, 8) void equaltime_kernel(
    const float* __restrict__ spikes,     // [B][PRE]
    const float* __restrict__ weights,    // [PRE][POST]
    const float* __restrict__ delays,     // [PRE][POST]
    const float* __restrict__ thresholds, // [POST]
    float* __restrict__ out)              // [B][POST]
{
    __shared__ __align__(16) float s_t[PRE];    // 4 KB sorted times
    __shared__ __align__(16) float s_w[PRE];    // 4 KB sorted weights
    __shared__ __align__(16) int   s_cnt[NBUCK];// 4 KB counts -> (off<<12|cnt)
    __shared__ int   s_isum[4];
    __shared__ float s_fw[4], s_fwt[4];
    __shared__ float s_red[4];

    const int tid  = threadIdx.x;
    const int lane = tid & 63;
    const int wid  = tid >> 6;

    // XCD-contiguous swizzle for weight/delay L2 locality
    const int bx   = blockIdx.x;
    const int sbx  = (bx & 7) * 256 + (bx >> 3);
    const int post = sbx >> 1;            // 2 WGs per post
    const int b0   = (sbx & 1) * B_PER_WG;
    const float theta = thresholds[post];

    // cache this post's delay/weight column in registers
    float dly[EPT], wgt[EPT];
#pragma unroll
    for (int j = 0; j < EPT; ++j) {
        int pre = tid * EPT + j;
        dly[j] = delays[pre * POST + post];
        wgt[j] = weights[pre * POST + post];
    }

    for (int bi = 0; bi < B_PER_WG; ++bi) {
        const int b = b0 + bi;

        // ---- zero counts ----
        reinterpret_cast<int4*>(s_cnt)[tid] = make_int4(0, 0, 0, 0);
        __syncthreads();                                        // Bz

        // ---- event times, bucket, arrival rank ----
        float4 sp = *reinterpret_cast<const float4*>(spikes + b * PRE + tid * EPT);
        float tv[EPT] = {sp.x + dly[0], sp.y + dly[1], sp.z + dly[2], sp.w + dly[3]};
        int bkt[EPT], rnk[EPT];
#pragma unroll
        for (int j = 0; j < EPT; ++j) {
            int k = (int)(tv[j] * 512.0f);        // t in [0,2)
            bkt[j] = k < NBUCK - 1 ? k : NBUCK - 1;
            rnk[j] = atomicAdd(&s_cnt[bkt[j]], 1);
        }
        __syncthreads();                                        // B1

        // ---- exclusive scan of counts -> packed (off<<12 | cnt) ----
        int4 cv = reinterpret_cast<int4*>(s_cnt)[tid];
        int c[EPT] = {cv.x, cv.y, cv.z, cv.w};
        int ls[EPT];
        int s = 0;
#pragma unroll
        for (int j = 0; j < EPT; ++j) { s += c[j]; ls[j] = s; }
        int x = wave_iscan_i32(s);
        if (lane == 63) s_isum[wid] = x;
        __syncthreads();                                        // B2
        int wbase = 0;
        for (int k2 = 0; k2 < wid; ++k2) wbase += s_isum[k2];
        int base = wbase + x - s;
        int4 pv;
        pv.x = ((base + ls[0] - c[0]) << 12) | c[0];
        pv.y = ((base + ls[1] - c[1]) << 12) | c[1];
        pv.z = ((base + ls[2] - c[2]) << 12) | c[2];
        pv.w = ((base + ls[3] - c[3]) << 12) | c[3];
        reinterpret_cast<int4*>(s_cnt)[tid] = pv;
        __syncthreads();                                        // B3

        // ---- scatter (split arrays: 4B writes, ~2-way aliasing = free) ----
#pragma unroll
        for (int j = 0; j < EPT; ++j) {
            int pos = (s_cnt[bkt[j]] >> 12) + rnk[j];
            s_t[pos] = tv[j];
            s_w[pos] = wgt[j];
        }
        __syncthreads();                                        // B4 (chunk-start)

        // ---- chunked fixup + scan + candidates with exact early exit ----
        float cumW = 0.f, cumWT = 0.f, mAll = INFINITY;
        for (int c0 = 0; c0 < PRE; c0 += CHUNK) {
            const int next = c0 + CHUNK;
            const int p = c0 + tid;

            // gather: exact in-bucket rank for buckets BASED in [c0,next)
            float e_t = s_t[p], e_w = s_w[p];
            int np = -1;
            {
                int k = (int)(e_t * 512.0f); k = k < NBUCK - 1 ? k : NBUCK - 1;
                int pk = s_cnt[k];
                int bas = pk >> 12, cnt = pk & 0xfff;
                if (bas >= c0 && cnt > 1) {
                    int r = 0;
                    for (int q = bas; q < bas + cnt; ++q) {
                        float tq = s_t[q];
                        r += ((tq < e_t) || (tq == e_t && q < p)) ? 1 : 0;
                    }
                    int tgt = bas + r;
                    if (tgt != p) np = tgt;
                }
            }
            // extension: tail of straddling buckets (positions [next, next+64))
            int np2 = -1; float e2t = 0.f, e2w = 0.f;
            if (tid < 64 && next + tid < PRE) {
                int p2 = next + tid;
                e2t = s_t[p2]; e2w = s_w[p2];
                int k = (int)(e2t * 512.0f); k = k < NBUCK - 1 ? k : NBUCK - 1;
                int pk = s_cnt[k];
                int bas = pk >> 12, cnt = pk & 0xfff;
                if (bas >= c0 && bas < next && cnt > 1) {
                    int r = 0;
                    for (int q = bas; q < bas + cnt; ++q) {
                        float tq = s_t[q];
                        r += ((tq < e2t) || (tq == e2t && q < p2)) ? 1 : 0;
                    }
                    int tgt = bas + r;
                    if (tgt != p2) np2 = tgt;
                }
            }
            __syncthreads();                                    // Bb: gathers done
            if (np  >= 0) { s_t[np]  = e_t;  s_w[np]  = e_w; }
            if (np2 >= 0) { s_t[np2] = e2t; s_w[np2] = e2w; }
            __syncthreads();                                    // Bc: fixup visible

            // exact boundary time: min t over positions >= next
            float t_next = INFINITY;
            if (next < PRE) {
                float tx = s_t[next];                 // uniform
                int kn = (int)(tx * 512.0f); kn = kn < NBUCK - 1 ? kn : NBUCK - 1;
                int pkn = s_cnt[kn];
                int basn = pkn >> 12, cntn = pkn & 0xfff;
                if (basn < next) {
                    t_next = tx;                       // sorted straddle: exact
                } else {
                    t_next = tx;                       // unsorted bucket: scan it
                    for (int q = basn; q < basn + cntn; ++q)
                        t_next = fminf(t_next, s_t[q]);
                }
            }

            // block scan of (w, w*t) over [c0, next)
            float t_p = s_t[p], w_p = s_w[p];
            float aw = w_p, awt = w_p * t_p;
            float xw  = wave_iscan_f32(aw);
            float xwt = wave_iscan_f32(awt);
            if (lane == 63) { s_fw[wid] = xw; s_fwt[wid] = xwt; }
            float tn = (p == PRE - 1) ? INFINITY
                     : (tid == TPB - 1) ? t_next : s_t[p + 1];
            __syncthreads();                                    // Bd: partials
            float W = cumW, WT = cumWT;
            for (int k2 = 0; k2 < wid; ++k2) { W += s_fw[k2]; WT += s_fwt[k2]; }
            W += xw; WT += xwt;
            cumW  += s_fw[0] + s_fw[1] + s_fw[2] + s_fw[3];
            cumWT += s_fwt[0] + s_fwt[1] + s_fwt[2] + s_fwt[3];

            // candidate
            float mc = INFINITY;
            if (W > 0.f) {
                float tmp = (theta + WT) * __builtin_amdgcn_rcpf(W);
                if (tmp >= t_p && tmp <= tn) mc = tmp;
            }
            mc = wave_min_f32(mc);
            if (lane == 0) s_red[wid] = mc;
            __syncthreads();                                    // Be (chunk-start next)
            mAll = fminf(mAll,
                   fminf(fminf(s_red[0], s_red[1]), fminf(s_red[2], s_red[3])));
            if (mAll <= t_next) break;   // later candidates >= t_k >= t_next
        }

        if (tid == 0) out[b * POST + post] = mAll;
        __syncthreads();                                        // protect s_cnt reuse
    }
}

extern "C" void kernel_launch(void* const* d_in, const int* in_sizes, int n_in,
                              void* d_out, int out_size, void* d_ws, size_t ws_size,
                              hipStream_t stream) {
    const float* spikes     = (const float*)d_in[0]; // [32,1024]
    const float* weights    = (const float*)d_in[1]; // [1024,1024]
    const float* delays     = (const float*)d_in[2]; // [1024,1024]
    const float* thresholds = (const float*)d_in[3]; // [1024]
    float* outp = (float*)d_out;                     // [32,1024]

    dim3 grid(POST * (B_TOT / B_PER_WG)); // 2048 workgroups
    dim3 block(TPB);
    equaltime_kernel<<<grid, block, 0, stream>>>(spikes, weights, delays, thresholds, outp);
}

// Round 6
// 140.220 us; speedup vs baseline: 1.5827x; 1.0609x over previous
//
#include <hip/hip_runtime.h>
#include <math.h>

// EqualtimeLayer: per (b,post): sort 1024 events by t = spike[b][pre]+delay[pre][post],
// prefix-sum (w, w*t) in sorted order, candidate tmp_k=(theta+cumwt)/cumw valid iff
// cumw>0 && tmp>=t_k && (k==last || tmp<=t_{k+1}); output = min valid tmp.
//
// R6: only events with t < T_CUT=0.625 (~20%, ~200 events) are bucketed/sorted;
// the rest contribute just their min time (exact epoch boundary). Crossing lands
// at t*~0.49 +- 0.05, so epoch 0 (1 chunk of 256, hole-padded) almost always
// terminates via the exact early-exit test. Rare exact fallback epoch sorts the
// tail over [0.625,2) with carried prefix sums — bit-exact overall.

#define B_TOT 32
#define PRE 1024
#define POST 1024
#define NBUCK 1024
#define TPB 256
#define EPT 4
#define BPW 8
#define CHUNK 256
#define KCUT 320            // include bucket k < 320  <=>  t < 0.625
#define TCUTF 0.625f

// ---- DPP helpers (gfx9 encodings) ----
template<int CTRL, int MASK>
__device__ __forceinline__ int dpp_add_i32(int v) {
    return v + __builtin_amdgcn_update_dpp(0, v, CTRL, MASK, 0xf, true);
}
template<int CTRL, int MASK>
__device__ __forceinline__ float dpp_add_f32(float v) {
    int t = __builtin_amdgcn_update_dpp(0, __float_as_int(v), CTRL, MASK, 0xf, true);
    return v + __int_as_float(t);
}
template<int CTRL>
__device__ __forceinline__ float dpp_min_f32(float v) {
    int t = __builtin_amdgcn_update_dpp(__float_as_int(v), __float_as_int(v), CTRL, 0xf, 0xf, false);
    return fminf(v, __int_as_float(t));
}
__device__ __forceinline__ int wave_iscan_i32(int v) {
    v = dpp_add_i32<0x111, 0xf>(v);
    v = dpp_add_i32<0x112, 0xf>(v);
    v = dpp_add_i32<0x114, 0xf>(v);
    v = dpp_add_i32<0x118, 0xf>(v);
    v = dpp_add_i32<0x142, 0xa>(v);
    v = dpp_add_i32<0x143, 0xc>(v);
    return v;
}
__device__ __forceinline__ float wave_iscan_f32(float v) {
    v = dpp_add_f32<0x111, 0xf>(v);
    v = dpp_add_f32<0x112, 0xf>(v);
    v = dpp_add_f32<0x114, 0xf>(v);
    v = dpp_add_f32<0x118, 0xf>(v);
    v = dpp_add_f32<0x142, 0xa>(v);
    v = dpp_add_f32<0x143, 0xc>(v);
    return v;
}
__device__ __forceinline__ float wave_min_f32(float v) {
    v = fminf(v, __shfl_down(v, 32));
    v = fminf(v, __shfl_down(v, 16));
    v = dpp_min_f32<0x140>(v);
    v = dpp_min_f32<0x141>(v);
    v = dpp_min_f32<0x4E>(v);
    v = dpp_min_f32<0xB1>(v);
    return v;
}
__device__ __forceinline__ int clampb(int k) {
    return k < 0 ? 0 : (k > NBUCK - 1 ? NBUCK - 1 : k);
}

// block-exclusive-scan NBUCK counts in s_cnt -> packed (off<<12|cnt); return total.
// Contains two __syncthreads (uniform call sites only).
__device__ __forceinline__ int scan_counts_block(int* s_cnt, int* s_isum,
                                                 int tid, int lane, int wid) {
    int4 cv = reinterpret_cast<int4*>(s_cnt)[tid];
    int c[4] = {cv.x, cv.y, cv.z, cv.w};
    int ls[4]; int s = 0;
#pragma unroll
    for (int j = 0; j < 4; ++j) { s += c[j]; ls[j] = s; }
    int x = wave_iscan_i32(s);
    if (lane == 63) s_isum[wid] = x;
    __syncthreads();
    int wbase = 0;
    for (int k = 0; k < wid; ++k) wbase += s_isum[k];
    int base = wbase + x - s;
    int4 pv;
    pv.x = ((base + ls[0] - c[0]) << 12) | c[0];
    pv.y = ((base + ls[1] - c[1]) << 12) | c[1];
    pv.z = ((base + ls[2] - c[2]) << 12) | c[2];
    pv.w = ((base + ls[3] - c[3]) << 12) | c[3];
    reinterpret_cast<int4*>(s_cnt)[tid] = pv;
    __syncthreads();
    return s_isum[0] + s_isum[1] + s_isum[2] + s_isum[3];
}

// Process aligned chunks [cStart,cEnd); valid data at positions >= posLo;
// candidates only for positions < posValidEnd; bucket index (t-t0f)*512,
// bucket base offset baseOff; epoch-end boundary time tEnd.
// Returns true if early-exited (answer final for this epoch chain).
__device__ __forceinline__ bool run_epoch(
    float* s_t, float* s_w, int* s_cnt, float* s_fw, float* s_fwt, float* s_red,
    int cStart, int cEnd, int posLo, int posValidEnd,
    float t0f, int baseOff, float tEnd, float theta,
    int tid, int lane, int wid, float& cumW, float& cumWT, float& mAll)
{
    for (int c0 = cStart; c0 < cEnd; c0 += CHUNK) {
        const int next = c0 + CHUNK;
        const int p = c0 + tid;
        const bool valid = (p >= posLo);

        // ---- fixup gather: exact in-bucket rank for buckets BASED in [c0,next) ----
        float e_t = s_t[p], e_w = s_w[p];
        int np = -1;
        if (valid) {
            int k = clampb((int)((e_t - t0f) * 512.0f));
            int pk = s_cnt[k];
            int bas = (pk >> 12) + baseOff, cnt = pk & 0xfff;
            if (bas >= c0 && cnt > 1) {
                int r = 0;
                for (int q = bas; q < bas + cnt; ++q) {
                    float tq = s_t[q];
                    r += ((tq < e_t) || (tq == e_t && q < p)) ? 1 : 0;
                }
                int tgt = bas + r;
                if (tgt != p) np = tgt;
            }
        }
        // straddle-extension: tail of chunk-based buckets in [next, next+64)
        int np2 = -1; float e2t = 0.f, e2w = 0.f;
        if (tid < 64) {
            int p2 = next + tid;
            if (p2 < cEnd && p2 >= posLo) {
                e2t = s_t[p2]; e2w = s_w[p2];
                int k = clampb((int)((e2t - t0f) * 512.0f));
                int pk = s_cnt[k];
                int bas = (pk >> 12) + baseOff, cnt = pk & 0xfff;
                if (bas >= c0 && bas < next && cnt > 1) {
                    int r = 0;
                    for (int q = bas; q < bas + cnt; ++q) {
                        float tq = s_t[q];
                        r += ((tq < e2t) || (tq == e2t && q < p2)) ? 1 : 0;
                    }
                    int tgt = bas + r;
                    if (tgt != p2) np2 = tgt;
                }
            }
        }
        __syncthreads();                                   // gathers done
        if (np  >= 0) { s_t[np]  = e_t;  s_w[np]  = e_w; }
        if (np2 >= 0) { s_t[np2] = e2t; s_w[np2] = e2w; }
        __syncthreads();                                   // fixup visible

        // ---- exact boundary: min t over positions >= next ----
        float t_next = tEnd;
        if (next < cEnd) {
            float tx = s_t[next];
            int k = clampb((int)((tx - t0f) * 512.0f));
            int pk = s_cnt[k];
            int bas = (pk >> 12) + baseOff, cnt = pk & 0xfff;
            t_next = tx;
            if (bas >= next) {   // bucket entirely in the future, still unsorted
                for (int q = bas; q < bas + cnt; ++q) t_next = fminf(t_next, s_t[q]);
            }                    // else: sorted straddle -> tx already exact
        }

        // ---- block scan of (w, w*t) over [c0, next) ----
        float t_p = s_t[p];
        float w_p = valid ? s_w[p] : 0.f;
        float aw = w_p, awt = w_p * t_p;
        float xw  = wave_iscan_f32(aw);
        float xwt = wave_iscan_f32(awt);
        if (lane == 63) { s_fw[wid] = xw; s_fwt[wid] = xwt; }
        float tn = (p == PRE - 1) ? INFINITY
                 : (tid == TPB - 1) ? t_next : s_t[p + 1];
        __syncthreads();                                   // partials visible
        float W = cumW, WT = cumWT;
        for (int k2 = 0; k2 < wid; ++k2) { W += s_fw[k2]; WT += s_fwt[k2]; }
        W += xw; WT += xwt;
        cumW  += s_fw[0] + s_fw[1] + s_fw[2] + s_fw[3];
        cumWT += s_fwt[0] + s_fwt[1] + s_fwt[2] + s_fwt[3];

        // ---- candidate + block min ----
        float mc = INFINITY;
        if (valid && p < posValidEnd && W > 0.f) {
            float tmp = (theta + WT) * __builtin_amdgcn_rcpf(W);
            if (tmp >= t_p && tmp <= tn) mc = tmp;
        }
        mc = wave_min_f32(mc);
        if (lane == 0) s_red[wid] = mc;
        __syncthreads();                                   // mins visible
        mAll = fminf(mAll,
               fminf(fminf(s_red[0], s_red[1]), fminf(s_red[2], s_red[3])));
        if (mAll <= t_next) return true;  // later candidates >= t_k >= t_next
    }
    return false;
}

__global__ __launch_bounds__(TPB, 8) void equaltime_kernel(
    const float* __restrict__ spikes,     // [B][PRE]
    const float* __restrict__ weights,    // [PRE][POST]
    const float* __restrict__ delays,     // [PRE][POST]
    const float* __restrict__ thresholds, // [POST]
    float* __restrict__ out)              // [B][POST]
{
    __shared__ __align__(16) float s_t[PRE];
    __shared__ __align__(16) float s_w[PRE];
    __shared__ __align__(16) int   s_cnt[NBUCK];
    __shared__ int   s_isum[4];
    __shared__ float s_fw[4], s_fwt[4];
    __shared__ float s_red[4];

    const int tid  = threadIdx.x;
    const int lane = tid & 63;
    const int wid  = tid >> 6;

    // XCD-contiguous swizzle for weight/delay L2 locality
    const int bx   = blockIdx.x;
    const int sbx  = (bx & 7) * 512 + (bx >> 3);
    const int post = sbx >> 2;            // 4 WGs per post
    const int b0   = (sbx & 3) * BPW;
    const float theta = thresholds[post];

    float dly[EPT], wgt[EPT];
#pragma unroll
    for (int j = 0; j < EPT; ++j) {
        int pre = tid * EPT + j;
        dly[j] = delays[pre * POST + post];
        wgt[j] = weights[pre * POST + post];
    }

    for (int bi = 0; bi < BPW; ++bi) {
        const int b = b0 + bi;

        // ---- zero counts ----
        reinterpret_cast<int4*>(s_cnt)[tid] = make_int4(0, 0, 0, 0);
        __syncthreads();

        // ---- times, buckets; only k<KCUT histogrammed; min of the rest ----
        float4 sp = *reinterpret_cast<const float4*>(spikes + b * PRE + tid * EPT);
        float tv[EPT] = {sp.x + dly[0], sp.y + dly[1], sp.z + dly[2], sp.w + dly[3]};
        int bkt[EPT], rnk[EPT];
        float mloc = INFINITY;
#pragma unroll
        for (int j = 0; j < EPT; ++j) {
            int k = (int)(tv[j] * 512.0f);
            bkt[j] = k;
            if (k < KCUT) rnk[j] = atomicAdd(&s_cnt[k], 1);
            else          mloc = fminf(mloc, tv[j]);
        }
        mloc = wave_min_f32(mloc);
        if (lane == 0) s_red[wid] = mloc;
        __syncthreads();

        const int N_low = scan_counts_block(s_cnt, s_isum, tid, lane, wid);
        const float minExcl = fminf(fminf(s_red[0], s_red[1]),
                                    fminf(s_red[2], s_red[3]));

        // ---- scatter included events; pad holes to chunk boundary ----
#pragma unroll
        for (int j = 0; j < EPT; ++j) {
            if (bkt[j] < KCUT) {
                int pos = (s_cnt[bkt[j]] >> 12) + rnk[j];
                s_t[pos] = tv[j];
                s_w[pos] = wgt[j];
            }
        }
        const int roundup = (N_low + CHUNK - 1) & ~(CHUNK - 1);
        int h = N_low + tid;
        if (h < roundup) { s_t[h] = minExcl; s_w[h] = 0.f; }
        __syncthreads();

        // ---- epoch 0: chunks over included events, exact early exit ----
        float cumW = 0.f, cumWT = 0.f, mAll = INFINITY;
        bool done = run_epoch(s_t, s_w, s_cnt, s_fw, s_fwt, s_red,
                              0, roundup, 0, N_low, 0.f, 0, minExcl, theta,
                              tid, lane, wid, cumW, cumWT, mAll);

        // ---- rare exact fallback: sort & process the excluded tail ----
        if (!done && N_low < PRE) {
            __syncthreads();
            reinterpret_cast<int4*>(s_cnt)[tid] = make_int4(0, 0, 0, 0);
            __syncthreads();
#pragma unroll
            for (int j = 0; j < EPT; ++j) {
                if (bkt[j] >= KCUT) {
                    int k2 = clampb((int)((tv[j] - TCUTF) * 512.0f));
                    bkt[j] = KCUT + k2;      // remember tail bucket (distinct range)
                    rnk[j] = atomicAdd(&s_cnt[k2], 1);
                }
            }
            __syncthreads();
            (void)scan_counts_block(s_cnt, s_isum, tid, lane, wid);
#pragma unroll
            for (int j = 0; j < EPT; ++j) {
                if (bkt[j] >= KCUT) {
                    int k2 = bkt[j] - KCUT;
                    int pos = N_low + (s_cnt[k2] >> 12) + rnk[j];
                    s_t[pos] = tv[j];
                    s_w[pos] = wgt[j];
                }
            }
            __syncthreads();
            done = run_epoch(s_t, s_w, s_cnt, s_fw, s_fwt, s_red,
                             N_low & ~(CHUNK - 1), PRE, N_low, PRE,
                             TCUTF, N_low, INFINITY, theta,
                             tid, lane, wid, cumW, cumWT, mAll);
        }

        if (tid == 0) out[b * POST + post] = mAll;
        __syncthreads();   // protect LDS reuse next batch
    }
}

extern "C" void kernel_launch(void* const* d_in, const int* in_sizes, int n_in,
                              void* d_out, int out_size, void* d_ws, size_t ws_size,
                              hipStream_t stream) {
    const float* spikes     = (const float*)d_in[0]; // [32,1024]
    const float* weights    = (const float*)d_in[1]; // [1024,1024]
    const float* delays     = (const float*)d_in[2]; // [1024,1024]
    const float* thresholds = (const float*)d_in[3]; // [1024]
    float* outp = (float*)d_out;                     // [32,1024]

    dim3 grid(POST * (B_TOT / BPW)); // 4096 workgroups
    dim3 block(TPB);
    equaltime_kernel<<<grid, block, 0, stream>>>(spikes, weights, delays, thresholds, outp);
}

// Round 8
// 132.267 us; speedup vs baseline: 1.6779x; 1.0601x over previous
//
#include <hip/hip_runtime.h>
#include <math.h>

// EqualtimeLayer: per (b,post): sort 1024 events by t = spike[b][pre]+delay[pre][post],
// prefix-sum (w, w*t) in sorted order, candidate tmp_k=(theta+cumwt)/cumw valid iff
// cumw>0 && tmp>=t_k && (k==last || tmp<=t_{k+1}); output = min valid tmp.
//
// R8 = R7 design with the races fixed:
//  - SPLIT raw/packed count buffers: hist atomics -> s_raw; redundant per-wave
//    scan READS s_raw only (wave 0 writes s_pck); wave 1 zeroes s_raw in the
//    scatter slot (all s_raw reads complete at B2). run_epoch reads s_pck only.
//  - Fallback epoch packs properly (wave 0) with explicit barriers (rare path).
// Only events t < 0.625 (~20%) are bucketed/sorted (512 buckets, width 1/819);
// the rest contribute their exact min time (epoch boundary). Crossing t*~0.49
// => epoch 0 is one 256-chunk with exact early exit. 7 barriers/batch common path.

#define B_TOT 32
#define PRE 1024
#define POST 1024
#define NB 512
#define TPB 256
#define EPT 4
#define BPW 8
#define CHUNK 256
#define TCUTF 0.625f
#define BSCALE 819.2f      // 512 buckets over [0, 0.625)

// ---- DPP helpers (gfx9 encodings) ----
template<int CTRL, int MASK>
__device__ __forceinline__ int dpp_add_i32(int v) {
    return v + __builtin_amdgcn_update_dpp(0, v, CTRL, MASK, 0xf, true);
}
template<int CTRL, int MASK>
__device__ __forceinline__ float dpp_add_f32(float v) {
    int t = __builtin_amdgcn_update_dpp(0, __float_as_int(v), CTRL, MASK, 0xf, true);
    return v + __int_as_float(t);
}
template<int CTRL>
__device__ __forceinline__ float dpp_min_f32(float v) {
    int t = __builtin_amdgcn_update_dpp(__float_as_int(v), __float_as_int(v), CTRL, 0xf, 0xf, false);
    return fminf(v, __int_as_float(t));
}
__device__ __forceinline__ int wave_iscan_i32(int v) {
    v = dpp_add_i32<0x111, 0xf>(v);
    v = dpp_add_i32<0x112, 0xf>(v);
    v = dpp_add_i32<0x114, 0xf>(v);
    v = dpp_add_i32<0x118, 0xf>(v);
    v = dpp_add_i32<0x142, 0xa>(v);
    v = dpp_add_i32<0x143, 0xc>(v);
    return v;
}
__device__ __forceinline__ float wave_iscan_f32(float v) {
    v = dpp_add_f32<0x111, 0xf>(v);
    v = dpp_add_f32<0x112, 0xf>(v);
    v = dpp_add_f32<0x114, 0xf>(v);
    v = dpp_add_f32<0x118, 0xf>(v);
    v = dpp_add_f32<0x142, 0xa>(v);
    v = dpp_add_f32<0x143, 0xc>(v);
    return v;
}
__device__ __forceinline__ float wave_min_f32(float v) {
    v = fminf(v, __shfl_down(v, 32));
    v = fminf(v, __shfl_down(v, 16));
    v = dpp_min_f32<0x140>(v);
    v = dpp_min_f32<0x141>(v);
    v = dpp_min_f32<0x4E>(v);
    v = dpp_min_f32<0xB1>(v);
    return v;
}
__device__ __forceinline__ int clampb(int k) {
    return k < 0 ? 0 : (k > NB - 1 ? NB - 1 : k);
}

// Redundant (every wave identical) exclusive scan of NB raw counts.
// READS raw only; wave 0 writes packed (off<<12|cnt) into pck (pck must not be
// read by anyone until the next barrier). Returns the total (uniform across
// waves: all read the same post-barrier raw data).
__device__ __forceinline__ int scan_counts(const int* raw, int* pck, int lane, int wid) {
    int4 v0 = reinterpret_cast<const int4*>(raw)[2 * lane];
    int4 v1 = reinterpret_cast<const int4*>(raw)[2 * lane + 1];
    int c[8] = {v0.x, v0.y, v0.z, v0.w, v1.x, v1.y, v1.z, v1.w};
    int ls[8]; int s = 0;
#pragma unroll
    for (int j = 0; j < 8; ++j) { s += c[j]; ls[j] = s; }
    int x = wave_iscan_i32(s);
    int excl = x - s;
    if (wid == 0) {
        int o[8];
#pragma unroll
        for (int j = 0; j < 8; ++j) o[j] = ((excl + ls[j] - c[j]) << 12) | c[j];
        reinterpret_cast<int4*>(pck)[2 * lane]     = make_int4(o[0], o[1], o[2], o[3]);
        reinterpret_cast<int4*>(pck)[2 * lane + 1] = make_int4(o[4], o[5], o[6], o[7]);
    }
    return __builtin_amdgcn_readlane(x, 63);
}

// Process aligned chunks [cStart,cEnd); valid data at positions >= posLo;
// candidates only for positions < posValidEnd; bucket = clamp((t-t0f)*BSCALE),
// bucket base offset baseOff; epoch-end boundary time tEnd. Uniform return.
__device__ __forceinline__ bool run_epoch(
    float* s_t, float* s_w, const int* pck, float* s_fw, float* s_fwt, float* s_red,
    int cStart, int cEnd, int posLo, int posValidEnd,
    float t0f, int baseOff, float tEnd, float theta,
    int tid, int lane, int wid, float& cumW, float& cumWT, float& mAll)
{
    for (int c0 = cStart; c0 < cEnd; c0 += CHUNK) {
        const int next = c0 + CHUNK;
        const int p = c0 + tid;
        const bool valid = (p >= posLo);

        // ---- fixup gather: exact in-bucket rank for buckets BASED in [c0,next) ----
        float e_t = s_t[p], e_w = s_w[p];
        int np = -1;
        if (valid) {
            int k = clampb((int)((e_t - t0f) * BSCALE));
            int pk = pck[k];
            int bas = (pk >> 12) + baseOff, cn = pk & 0xfff;
            if (bas >= c0 && cn > 1) {
                int r = 0;
                for (int q = bas; q < bas + cn; ++q) {
                    float tq = s_t[q];
                    r += ((tq < e_t) || (tq == e_t && q < p)) ? 1 : 0;
                }
                int tgt = bas + r;
                if (tgt != p) np = tgt;
            }
        }
        // straddle-extension: tail of chunk-based buckets in [next, next+64)
        // (bucket count > 64 would escape; impossible at lambda<=0.75)
        int np2 = -1; float e2t = 0.f, e2w = 0.f;
        if (tid < 64) {
            int p2 = next + tid;
            if (p2 < cEnd && p2 >= posLo) {
                e2t = s_t[p2]; e2w = s_w[p2];
                int k = clampb((int)((e2t - t0f) * BSCALE));
                int pk = pck[k];
                int bas = (pk >> 12) + baseOff, cn = pk & 0xfff;
                if (bas >= c0 && bas < next && cn > 1) {
                    int r = 0;
                    for (int q = bas; q < bas + cn; ++q) {
                        float tq = s_t[q];
                        r += ((tq < e2t) || (tq == e2t && q < p2)) ? 1 : 0;
                    }
                    int tgt = bas + r;
                    if (tgt != p2) np2 = tgt;
                }
            }
        }
        __syncthreads();                                   // B: all gathers done
        if (np  >= 0) { s_t[np]  = e_t;  s_w[np]  = e_w; }
        if (np2 >= 0) { s_t[np2] = e2t; s_w[np2] = e2w; }
        __syncthreads();                                   // B: fixup visible

        // ---- exact boundary: min t over positions >= next ----
        float t_next = tEnd;
        if (next < cEnd) {
            float tx = s_t[next];
            int k = clampb((int)((tx - t0f) * BSCALE));
            int pk = pck[k];
            int bas = (pk >> 12) + baseOff, cn = pk & 0xfff;
            t_next = tx;                 // sorted straddle (bas<next): exact
            if (bas >= next) {           // bucket starts at next, unsorted: scan it
                for (int q = bas; q < bas + cn; ++q) t_next = fminf(t_next, s_t[q]);
            }
        }

        // ---- block scan of (w, w*t) over [c0, next) ----
        float t_p = s_t[p];
        float w_p = valid ? s_w[p] : 0.f;
        float aw = w_p, awt = w_p * t_p;
        float xw  = wave_iscan_f32(aw);
        float xwt = wave_iscan_f32(awt);
        if (lane == 63) { s_fw[wid] = xw; s_fwt[wid] = xwt; }
        float tn = (p == PRE - 1) ? INFINITY
                 : (tid == TPB - 1) ? t_next : s_t[p + 1];
        __syncthreads();                                   // B: partials visible
        float W = cumW, WT = cumWT;
        for (int k2 = 0; k2 < wid; ++k2) { W += s_fw[k2]; WT += s_fwt[k2]; }
        W += xw; WT += xwt;
        cumW  += s_fw[0] + s_fw[1] + s_fw[2] + s_fw[3];
        cumWT += s_fwt[0] + s_fwt[1] + s_fwt[2] + s_fwt[3];

        // ---- candidate + block min ----
        float mc = INFINITY;
        if (valid && p < posValidEnd && W > 0.f) {
            float tmp = (theta + WT) * __builtin_amdgcn_rcpf(W);
            if (tmp >= t_p && tmp <= tn) mc = tmp;
        }
        mc = wave_min_f32(mc);
        if (lane == 0) s_red[wid] = mc;
        __syncthreads();                                   // B: mins visible
        mAll = fminf(mAll,
               fminf(fminf(s_red[0], s_red[1]), fminf(s_red[2], s_red[3])));
        if (mAll <= t_next) return true;  // later candidates >= t_k >= t_next
    }
    return false;
}

__global__ __launch_bounds__(TPB, 8) void equaltime_kernel(
    const float* __restrict__ spikes,     // [B][PRE]
    const float* __restrict__ weights,    // [PRE][POST]
    const float* __restrict__ delays,     // [PRE][POST]
    const float* __restrict__ thresholds, // [POST]
    float* __restrict__ out)              // [B][POST]
{
    __shared__ __align__(16) float s_t[PRE];   // 4 KB
    __shared__ __align__(16) float s_w[PRE];   // 4 KB
    __shared__ __align__(16) int   s_raw[NB];  // 2 KB raw counts (hist target)
    __shared__ __align__(16) int   s_pck[NB];  // 2 KB packed (off<<12|cnt)
    __shared__ float s_fw[4], s_fwt[4];
    __shared__ float s_red[4];

    const int tid  = threadIdx.x;
    const int lane = tid & 63;
    const int wid  = tid >> 6;

    // XCD-contiguous swizzle for weight/delay L2 locality
    const int bx   = blockIdx.x;
    const int sbx  = (bx & 7) * 512 + (bx >> 3);
    const int post = sbx >> 2;            // 4 WGs per post
    const int b0   = (sbx & 3) * BPW;
    const float theta = thresholds[post];

    float dly[EPT], wgt[EPT];
#pragma unroll
    for (int j = 0; j < EPT; ++j) {
        int pre = tid * EPT + j;
        dly[j] = delays[pre * POST + post];
        wgt[j] = weights[pre * POST + post];
    }

    // zero raw counts once (subsequent batches re-zero in the scatter slot)
    reinterpret_cast<int2*>(s_raw)[tid] = make_int2(0, 0);
    __syncthreads();

    for (int bi = 0; bi < BPW; ++bi) {
        const int b = b0 + bi;

        // ---- times; hist of t<TCUT into s_raw; min of the rest ----
        float4 sp = *reinterpret_cast<const float4*>(spikes + b * PRE + tid * EPT);
        float tv[EPT] = {sp.x + dly[0], sp.y + dly[1], sp.z + dly[2], sp.w + dly[3]};
        int bkt[EPT], rnk[EPT];
        float mloc = INFINITY;
#pragma unroll
        for (int j = 0; j < EPT; ++j) {
            int k = (int)(tv[j] * BSCALE);
            bkt[j] = k;
            if (k < NB) rnk[j] = atomicAdd(&s_raw[k], 1);
            else        mloc = fminf(mloc, tv[j]);
        }
        mloc = wave_min_f32(mloc);
        __syncthreads();                                   // B1: counts final

        if (lane == 0) s_red[wid] = mloc;                  // safe: post-B1 write,
                                                           // read post-B2
        const int N_low = scan_counts(s_raw, s_pck, lane, wid); // reads raw only
        __syncthreads();                                   // B2: pck + s_red visible

        const float minExcl = fminf(fminf(s_red[0], s_red[1]),
                                    fminf(s_red[2], s_red[3]));
        // ---- scatter included (reads s_pck); pad holes; wave1 zeroes s_raw ----
#pragma unroll
        for (int j = 0; j < EPT; ++j) {
            if (bkt[j] < NB) {
                int pos = (s_pck[bkt[j]] >> 12) + rnk[j];
                s_t[pos] = tv[j];
                s_w[pos] = wgt[j];
            }
        }
        if (wid == 1) {   // all s_raw reads completed at B2
            reinterpret_cast<int4*>(s_raw)[2 * lane]     = make_int4(0, 0, 0, 0);
            reinterpret_cast<int4*>(s_raw)[2 * lane + 1] = make_int4(0, 0, 0, 0);
        }
        const int roundup = (N_low + CHUNK - 1) & ~(CHUNK - 1);
        int h = N_low + tid;
        if (h < roundup) { s_t[h] = minExcl; s_w[h] = 0.f; }
        __syncthreads();                                   // B3: scatter+zero visible

        // ---- epoch 0 (typically one chunk, exact early exit) ----
        float cumW = 0.f, cumWT = 0.f, mAll = INFINITY;
        bool done = run_epoch(s_t, s_w, s_pck, s_fw, s_fwt, s_red,
                              0, roundup, 0, N_low, 0.f, 0, minExcl, theta,
                              tid, lane, wid, cumW, cumWT, mAll);

        // ---- rare exact fallback: sort & process the excluded tail ----
        if (!done && N_low < PRE) {
            // s_raw is zeroed; s_pck is dead (epoch 0 finished)
#pragma unroll
            for (int j = 0; j < EPT; ++j) {
                if (bkt[j] >= NB) {
                    int k2 = clampb((int)((tv[j] - TCUTF) * BSCALE));
                    bkt[j] = NB + k2;          // remember tail bucket
                    rnk[j] = atomicAdd(&s_raw[k2], 1);
                }
            }
            __syncthreads();                               // counts final
            (void)scan_counts(s_raw, s_pck, lane, wid);    // wave 0 packs
            __syncthreads();                               // pck visible
#pragma unroll
            for (int j = 0; j < EPT; ++j) {
                if (bkt[j] >= NB) {
                    int k2 = bkt[j] - NB;
                    int pos = N_low + (s_pck[k2] >> 12) + rnk[j];
                    s_t[pos] = tv[j];
                    s_w[pos] = wgt[j];
                }
            }
            if (wid == 1) {   // re-zero raw for the next batch
                reinterpret_cast<int4*>(s_raw)[2 * lane]     = make_int4(0, 0, 0, 0);
                reinterpret_cast<int4*>(s_raw)[2 * lane + 1] = make_int4(0, 0, 0, 0);
            }
            __syncthreads();                               // scatter+zero visible
            run_epoch(s_t, s_w, s_pck, s_fw, s_fwt, s_red,
                      N_low & ~(CHUNK - 1), PRE, N_low, PRE,
                      TCUTF, N_low, INFINITY, theta,
                      tid, lane, wid, cumW, cumWT, mAll);
        }

        if (tid == 0) out[b * POST + post] = mAll;
        // No trailing barrier needed: next batch's hist atomics target s_raw,
        // whose zeroing was barrier-ordered (B3 / fallback barrier) before any
        // post-barrier reader, and run_epoch reads only s_t/s_w/s_pck.
    }
}

extern "C" void kernel_launch(void* const* d_in, const int* in_sizes, int n_in,
                              void* d_out, int out_size, void* d_ws, size_t ws_size,
                              hipStream_t stream) {
    const float* spikes     = (const float*)d_in[0]; // [32,1024]
    const float* weights    = (const float*)d_in[1]; // [1024,1024]
    const float* delays     = (const float*)d_in[2]; // [1024,1024]
    const float* thresholds = (const float*)d_in[3]; // [1024]
    float* outp = (float*)d_out;                     // [32,1024]

    dim3 grid(POST * (B_TOT / BPW)); // 4096 workgroups
    dim3 block(TPB);
    equaltime_kernel<<<grid, block, 0, stream>>>(spikes, weights, delays, thresholds, outp);
}